// Round 1
// baseline (346.890 us; speedup 1.0000x reference)
//
#include <hip/hip_runtime.h>

#define N_PED 8192
#define HID 128
#define NN 36
#define I_PER_BLOCK 32
#define SLICES 16
#define BLOCK 512               // I_PER_BLOCK * SLICES
#define JS (N_PED / SLICES)     // 512 j's per thread
#define HSTRIDE 37              // 36 bins + 1 trash slot; odd stride for banks
#define NBLOCKS (N_PED / I_PER_BLOCK)  // 256

__global__ __launch_bounds__(BLOCK, 1) void pool_kernel(
    const float* __restrict__ obs2_g,   // [8192][2]
    const float* __restrict__ W,        // [128][36] row-major
    const float* __restrict__ bias,     // [128]
    float* __restrict__ out)            // [8192][128]
{
    // Region A: 64KB — obs2 during histogram, W during GEMM epilogue
    __shared__ float4 s_a4[N_PED / 2];                 // 65536 B
    __shared__ float  s_hist[BLOCK * HSTRIDE];         // 75776 B
    __shared__ float  s_rgrid[I_PER_BLOCK][NN];        //  4608 B
    __shared__ float  s_sub[I_PER_BLOCK];              //   128 B

    const int tid = threadIdx.x;
    const int bid = blockIdx.x;

    // ---- Phase 0: stage obs2 (all 8192 points) into LDS + zero histograms
    {
        const float4* og4 = (const float4*)obs2_g;     // 4096 float4
        #pragma unroll
        for (int k = 0; k < (N_PED / 2) / BLOCK; ++k)
            s_a4[tid + k * BLOCK] = og4[tid + k * BLOCK];
        #pragma unroll
        for (int k = 0; k < HSTRIDE; ++k)
            s_hist[tid + k * BLOCK] = 0.0f;
    }
    __syncthreads();

    // ---- Phase 1: pairwise occupancy histogram
    const int il    = tid & (I_PER_BLOCK - 1);
    const int slice = tid >> 5;                        // 0..15
    const int i     = bid * I_PER_BLOCK + il;

    const float2* s_obs2 = (const float2*)s_a4;
    const float2  pi = s_obs2[i];
    const float   xi = pi.x, yi = pi.y;

    // self-pair validity flag (subtract 1 from bin 21 iff obs2[i] finite)
    if (slice == 0)
        s_sub[il] = (xi == xi) ? 1.0f : 0.0f;

    const int hbase = tid * HSTRIDE;
    const int j0 = slice * JS;

    #define PAIR(px, py) do {                                   \
        float dx = ((px) - xi) + 3.0f;                          \
        float dy = ((py) - yi) + 3.0f;                          \
        bool in_r = (dx >= 0.0f) & (dx < 6.0f) &                \
                    (dy >= 0.0f) & (dy < 6.0f);                 \
        int bin = in_r ? ((int)dx * 6 + (int)dy) : NN;          \
        atomicAdd(&s_hist[hbase + bin], 1.0f);                  \
    } while (0)

    for (int j = j0; j < j0 + JS; j += 4) {
        float4 q0 = s_a4[(j >> 1) + 0];
        float4 q1 = s_a4[(j >> 1) + 1];
        PAIR(q0.x, q0.y);
        PAIR(q0.z, q0.w);
        PAIR(q1.x, q1.y);
        PAIR(q1.z, q1.w);
    }
    #undef PAIR
    __syncthreads();

    // ---- Phase 2: reduce 16 slice-histograms per i; stage W into region A
    for (int idx = tid; idx < I_PER_BLOCK * NN; idx += BLOCK) {
        int ril = idx / NN;
        int c   = idx - ril * NN;
        float s = 0.0f;
        #pragma unroll
        for (int sl = 0; sl < SLICES; ++sl)
            s += s_hist[(sl * I_PER_BLOCK + ril) * HSTRIDE + c];
        if (c == 21) s -= s_sub[ril];   // remove self-pair (rel = (3,3))
        s_rgrid[ril][c] = s;
    }
    {
        const float4* W4  = (const float4*)W;          // 1152 float4
        float4*       sW4 = s_a4;
        for (int k = tid; k < (HID * NN) / 4; k += BLOCK)
            sW4[k] = W4[k];
    }
    __syncthreads();

    // ---- Phase 3: out[i][h] = sum_k rgrid[i][k] * W[h][k] + b[h]
    const int h0  = tid & 15;           // h = h0 + 16*hh  (bank-friendly)
    const int gil = tid >> 4;           // 0..31
    const float* sW = (const float*)s_a4;

    float g[NN];
    {
        const float4* rg4 = (const float4*)s_rgrid[gil];
        #pragma unroll
        for (int k4 = 0; k4 < 9; ++k4) {
            float4 v = rg4[k4];
            g[k4 * 4 + 0] = v.x; g[k4 * 4 + 1] = v.y;
            g[k4 * 4 + 2] = v.z; g[k4 * 4 + 3] = v.w;
        }
    }

    float acc[8];
    #pragma unroll
    for (int hh = 0; hh < 8; ++hh)
        acc[hh] = bias[h0 + hh * 16];

    #pragma unroll
    for (int hh = 0; hh < 8; ++hh) {
        const int h = h0 + hh * 16;
        const float4* wrow = (const float4*)(sW + h * NN);  // 144B rows, 16B aligned
        #pragma unroll
        for (int k4 = 0; k4 < 9; ++k4) {
            float4 w = wrow[k4];
            acc[hh] += g[k4 * 4 + 0] * w.x + g[k4 * 4 + 1] * w.y
                     + g[k4 * 4 + 2] * w.z + g[k4 * 4 + 3] * w.w;
        }
    }

    const int oi = bid * I_PER_BLOCK + gil;
    #pragma unroll
    for (int hh = 0; hh < 8; ++hh)
        out[oi * HID + h0 + hh * 16] = acc[hh];
}

extern "C" void kernel_launch(void* const* d_in, const int* in_sizes, int n_in,
                              void* d_out, int out_size, void* d_ws, size_t ws_size,
                              hipStream_t stream) {
    // inputs: 0=hidden_state (unused), 1=obs1 (unused), 2=obs2, 3=W, 4=b
    const float* obs2 = (const float*)d_in[2];
    const float* W    = (const float*)d_in[3];
    const float* b    = (const float*)d_in[4];
    float* out        = (float*)d_out;
    (void)in_sizes; (void)n_in; (void)out_size; (void)d_ws; (void)ws_size;

    hipLaunchKernelGGL(pool_kernel, dim3(NBLOCKS), dim3(BLOCK), 0, stream,
                       obs2, W, b, out);
}

// Round 2
// 52.661 us; speedup vs baseline: 6.5872x; 6.5872x over previous
//
#include <hip/hip_runtime.h>

#define N_PED 8192
#define HID 128
#define NN 36
#define I_PER_BLOCK 32
#define SLICES 16
#define BLOCK 512               // I_PER_BLOCK * SLICES
#define JS (N_PED / SLICES)     // 512 j's per thread
#define HW 19                   // packed words/thread: 18 bin-pairs + 1 trash
#define NBLOCKS (N_PED / I_PER_BLOCK)  // 256

__global__ __launch_bounds__(BLOCK, 1) void pool_kernel(
    const float* __restrict__ obs2_g,   // [8192][2]
    const float* __restrict__ W,        // [128][36] row-major
    const float* __restrict__ bias,     // [128]
    float* __restrict__ out)            // [8192][128]
{
    // Region A: 64KB — obs2 during histogram, W during GEMM epilogue
    __shared__ float4   s_a4[N_PED / 2];               // 65536 B
    __shared__ unsigned s_hA[BLOCK * HW];              // 38912 B
    __shared__ unsigned s_hB[BLOCK * HW];              // 38912 B
    __shared__ float    s_rgrid[I_PER_BLOCK][NN];      //  4608 B
    __shared__ unsigned s_sub[I_PER_BLOCK];            //   128 B
    // total 148,096 B -> 1 block/CU

    const int tid = threadIdx.x;
    const int bid = blockIdx.x;

    // ---- Phase 0: stage obs2 into LDS + zero histograms
    {
        const float4* og4 = (const float4*)obs2_g;     // 4096 float4
        #pragma unroll
        for (int k = 0; k < (N_PED / 2) / BLOCK; ++k)  // 8
            s_a4[tid + k * BLOCK] = og4[tid + k * BLOCK];
        #pragma unroll
        for (int k = 0; k < HW; ++k) {
            s_hA[tid + k * BLOCK] = 0u;
            s_hB[tid + k * BLOCK] = 0u;
        }
    }
    __syncthreads();

    // ---- Phase 1: pairwise occupancy histogram (private, packed u16x2, non-atomic)
    const int il    = tid & (I_PER_BLOCK - 1);
    const int slice = tid >> 5;                        // 0..15
    const int i     = bid * I_PER_BLOCK + il;

    const float2* s_p = (const float2*)s_a4;
    const float2  pi  = s_p[i];
    const float   xi3 = pi.x - 3.0f;
    const float   yi3 = pi.y - 3.0f;

    if (slice == 0)
        s_sub[il] = (pi.x == pi.x) ? 1u : 0u;          // self-pair valid flag

    const int hbase = tid * HW;
    const int j0 = slice * JS;

    // word = 3*ix + (iy>>1), half = iy&1  (bin = 6*ix+iy; 6*ix even)
    // out-of-range/NaN -> trash word 18 (never read back)
    #define PAIR(H, px, py) do {                                    \
        float dx = (px) - xi3;                                      \
        float dy = (py) - yi3;                                      \
        bool in_r = (dx >= 0.0f) && (dx < 6.0f) &&                  \
                    (dy >= 0.0f) && (dy < 6.0f);                    \
        int ix = (int)dx;                                           \
        int iy = (int)dy;                                           \
        int w  = in_r ? (ix * 3 + (iy >> 1)) : 18;                  \
        unsigned inc = (iy & 1) ? 0x10000u : 1u;                    \
        unsigned v = H[hbase + w];                                  \
        H[hbase + w] = v + inc;                                     \
    } while (0)

    for (int j = j0; j < j0 + JS; j += 8) {
        int q = j >> 1;
        float4 q0 = s_a4[q + 0];
        float4 q1 = s_a4[q + 1];
        float4 q2 = s_a4[q + 2];
        float4 q3 = s_a4[q + 3];
        PAIR(s_hA, q0.x, q0.y); PAIR(s_hB, q0.z, q0.w);
        PAIR(s_hA, q1.x, q1.y); PAIR(s_hB, q1.z, q1.w);
        PAIR(s_hA, q2.x, q2.y); PAIR(s_hB, q2.z, q2.w);
        PAIR(s_hA, q3.x, q3.y); PAIR(s_hB, q3.z, q3.w);
    }
    #undef PAIR
    __syncthreads();

    // ---- Phase 2: reduce packed words over 16 slices x 2 banks; stage W
    for (int idx = tid; idx < I_PER_BLOCK * 18; idx += BLOCK) {   // 576 tasks
        int ril = idx / 18;
        int w   = idx - ril * 18;
        unsigned s = 0u;
        #pragma unroll
        for (int sl = 0; sl < SLICES; ++sl) {
            int t = sl * I_PER_BLOCK + ril;
            s += s_hA[t * HW + w] + s_hB[t * HW + w];
        }
        unsigned lo = s & 0xFFFFu;      // bin = 6*ix + 2*(w%3)
        unsigned hi = s >> 16;          // bin = 6*ix + 2*(w%3) + 1
        if (w == 10) hi -= s_sub[ril];  // self-pair lands in bin 21 (ix=3,iy=3)
        int ix = w / 3, r3 = w - ix * 3;
        int c  = ix * 6 + r3 * 2;
        s_rgrid[ril][c    ] = (float)lo;
        s_rgrid[ril][c + 1] = (float)hi;
    }
    {
        const float4* W4  = (const float4*)W;          // 1152 float4
        for (int k = tid; k < (HID * NN) / 4; k += BLOCK)
            s_a4[k] = W4[k];
    }
    __syncthreads();

    // ---- Phase 3: out[i][h] = sum_k rgrid[i][k] * W[h][k] + b[h]
    const int h0  = tid & 15;           // h = h0 + 16*hh
    const int gil = tid >> 4;           // 0..31
    const float* sW = (const float*)s_a4;

    float g[NN];
    {
        const float4* rg4 = (const float4*)s_rgrid[gil];
        #pragma unroll
        for (int k4 = 0; k4 < 9; ++k4) {
            float4 v = rg4[k4];
            g[k4 * 4 + 0] = v.x; g[k4 * 4 + 1] = v.y;
            g[k4 * 4 + 2] = v.z; g[k4 * 4 + 3] = v.w;
        }
    }

    float acc[8];
    #pragma unroll
    for (int hh = 0; hh < 8; ++hh)
        acc[hh] = bias[h0 + hh * 16];

    #pragma unroll
    for (int hh = 0; hh < 8; ++hh) {
        const int h = h0 + hh * 16;
        const float4* wrow = (const float4*)(sW + h * NN);  // 144B rows, 16B aligned
        #pragma unroll
        for (int k4 = 0; k4 < 9; ++k4) {
            float4 w = wrow[k4];
            acc[hh] += g[k4 * 4 + 0] * w.x + g[k4 * 4 + 1] * w.y
                     + g[k4 * 4 + 2] * w.z + g[k4 * 4 + 3] * w.w;
        }
    }

    const int oi = bid * I_PER_BLOCK + gil;
    #pragma unroll
    for (int hh = 0; hh < 8; ++hh)
        out[oi * HID + h0 + hh * 16] = acc[hh];
}

extern "C" void kernel_launch(void* const* d_in, const int* in_sizes, int n_in,
                              void* d_out, int out_size, void* d_ws, size_t ws_size,
                              hipStream_t stream) {
    // inputs: 0=hidden_state (unused), 1=obs1 (unused), 2=obs2, 3=W, 4=b
    const float* obs2 = (const float*)d_in[2];
    const float* W    = (const float*)d_in[3];
    const float* b    = (const float*)d_in[4];
    float* out        = (float*)d_out;
    (void)in_sizes; (void)n_in; (void)out_size; (void)d_ws; (void)ws_size;

    hipLaunchKernelGGL(pool_kernel, dim3(NBLOCKS), dim3(BLOCK), 0, stream,
                       obs2, W, b, out);
}

// Round 3
// 41.436 us; speedup vs baseline: 8.3717x; 1.2709x over previous
//
#include <hip/hip_runtime.h>

#define N_PED  8192
#define HID    128
#define NN     36
#define IPB    16            // i-rows per block
#define SLICES 32            // j-slices per block (one per 16-thread group)
#define BLOCK  512           // IPB * SLICES
#define JS     256           // j's per thread (8192/32)
#define HW     10            // packed words/thread: 9 bin-words (36 bytes) + 1 trash
#define HPAD   3200          // pad words so 3 blocks don't fit in 160KB LDS (balance at 2/CU)
#define NB     512           // 8192 / IPB

__global__ __launch_bounds__(BLOCK, 4) void pool_kernel(
    const float* __restrict__ obs2_g,   // [8192][2]
    const float* __restrict__ Wg,       // [128][36] row-major
    const float* __restrict__ bias,     // [128]
    float* __restrict__ out)            // [8192][128]
{
    __shared__ unsigned s_hA[HW * BLOCK + HPAD];   // 33,280 B (incl. pad)
    __shared__ unsigned s_hB[HW * BLOCK];          // 20,480 B
    __shared__ float    s_rgrid[IPB][NN];          //  2,304 B
    __shared__ unsigned s_wsel[IPB];               //     64 B
    // ~56.1 KB -> exactly 2 blocks/CU on 160KB LDS

    const int tid = threadIdx.x;
    const int bid = blockIdx.x;

    // ---- Phase 0: zero histograms (bank-striped, conflict-free)
    #pragma unroll
    for (int k = 0; k < HW; ++k) {
        s_hA[tid + k * BLOCK] = 0u;
        s_hB[tid + k * BLOCK] = 0u;
    }

    // ---- per-thread row setup
    const int il    = tid & (IPB - 1);
    const int slice = tid >> 4;                    // 0..31
    const int i     = bid * IPB + il;

    const float2 pi = ((const float2*)obs2_g)[i];
    const float  xi4 = pi.x - 4.0f;
    const float  yi4 = pi.y - 4.0f;

    // self-pair bin via IDENTICAL arithmetic (handles fl(xi - fl(xi-4)) != 4)
    if (tid < IPB) {
        float dx = pi.x - xi4;                     // ~4.0
        float dy = pi.y - yi4;
        unsigned u1 = (unsigned)((int)dx) - 1u;
        unsigned u2 = (unsigned)((int)dy) - 1u;
        bool ok = (u1 < 6u) & (u2 < 6u);           // false iff NaN/inf row
        s_wsel[il] = ok ? (u1 * 6u + u2) : 255u;
    }
    __syncthreads();

    // ---- Phase 1: pairwise occupancy histogram
    // bin = u1*6+u2 (byte index 0..35); word = bin>>2; byte = bin&3; trash word 9.
    const int tid4 = tid * 4;                      // byte offset of lane column

    #define PAIR(H, px, py) do {                                    \
        float dx = (px) - xi4;                                      \
        float dy = (py) - yi4;                                      \
        unsigned u1 = (unsigned)((int)dx) - 1u;                     \
        unsigned u2 = (unsigned)((int)dy) - 1u;                     \
        unsigned bin = u1 * 6u + u2;                                \
        unsigned w  = ((u1 < 6u) & (u2 < 6u)) ? (bin >> 2) : 9u;    \
        unsigned sh = (bin & 3u) << 3;                              \
        H[w * BLOCK + tid] += (1u << sh);                           \
    } while (0)

    {
        const float4* jp = (const float4*)obs2_g + slice * (JS / 2);  // 128 float4/slice
        float4 q0 = jp[0], q1 = jp[1], q2 = jp[2], q3 = jp[3];
        for (int it = 0; it < JS / 8 - 1; ++it) {
            float4 n0 = jp[4], n1 = jp[5], n2 = jp[6], n3 = jp[7];
            jp += 4;
            PAIR(s_hA, q0.x, q0.y); PAIR(s_hB, q0.z, q0.w);
            PAIR(s_hA, q1.x, q1.y); PAIR(s_hB, q1.z, q1.w);
            PAIR(s_hA, q2.x, q2.y); PAIR(s_hB, q2.z, q2.w);
            PAIR(s_hA, q3.x, q3.y); PAIR(s_hB, q3.z, q3.w);
            q0 = n0; q1 = n1; q2 = n2; q3 = n3;
        }
        PAIR(s_hA, q0.x, q0.y); PAIR(s_hB, q0.z, q0.w);
        PAIR(s_hA, q1.x, q1.y); PAIR(s_hB, q1.z, q1.w);
        PAIR(s_hA, q2.x, q2.y); PAIR(s_hB, q2.z, q2.w);
        PAIR(s_hA, q3.x, q3.y); PAIR(s_hB, q3.z, q3.w);
    }
    #undef PAIR
    __syncthreads();

    // ---- Phase 2: byte-wise reduce over 32 slices x 2 arrays (144 tasks)
    if (tid < IPB * (HW - 1)) {                    // 144
        const int ril = tid & (IPB - 1);
        const int w   = tid >> 4;                  // 0..8
        unsigned lo = 0u, hi = 0u;                 // 2x u16 lanes each (max 64*128)
        #pragma unroll 8
        for (int sl = 0; sl < SLICES; ++sl) {
            unsigned t = sl * IPB + ril;
            unsigned a = s_hA[w * BLOCK + t];
            unsigned b = s_hB[w * BLOCK + t];
            lo += (a & 0x00FF00FFu) + (b & 0x00FF00FFu);
            hi += ((a >> 8) & 0x00FF00FFu) + ((b >> 8) & 0x00FF00FFu);
        }
        unsigned s0 = lo & 0xFFFFu;
        unsigned s1 = hi & 0xFFFFu;
        unsigned s2 = lo >> 16;
        unsigned s3 = hi >> 16;
        const unsigned sel = s_wsel[ril];
        const unsigned base = (unsigned)(w * 4);
        s0 -= (sel == base + 0u);
        s1 -= (sel == base + 1u);
        s2 -= (sel == base + 2u);
        s3 -= (sel == base + 3u);
        s_rgrid[ril][base + 0] = (float)s0;
        s_rgrid[ril][base + 1] = (float)s1;
        s_rgrid[ril][base + 2] = (float)s2;
        s_rgrid[ril][base + 3] = (float)s3;
    }
    __syncthreads();

    // ---- Phase 3: fused GEMM  out[i][h] = sum_k grid[i][k]*W[h][k] + b[h]
    const int h  = tid & (HID - 1);                // 0..127
    const int rq = tid >> 7;                       // 0..3 (wave-uniform)
    const float4* W4 = (const float4*)Wg;          // [128][9] float4

    const float bh = bias[h];
    float acc0 = bh, acc1 = bh, acc2 = bh, acc3 = bh;

    #pragma unroll
    for (int k4 = 0; k4 < 9; ++k4) {
        float4 w4 = W4[h * 9 + k4];
        float4 g0 = *(const float4*)&s_rgrid[rq     ][k4 * 4];
        float4 g1 = *(const float4*)&s_rgrid[rq +  4][k4 * 4];
        float4 g2 = *(const float4*)&s_rgrid[rq +  8][k4 * 4];
        float4 g3 = *(const float4*)&s_rgrid[rq + 12][k4 * 4];
        acc0 += g0.x * w4.x + g0.y * w4.y + g0.z * w4.z + g0.w * w4.w;
        acc1 += g1.x * w4.x + g1.y * w4.y + g1.z * w4.z + g1.w * w4.w;
        acc2 += g2.x * w4.x + g2.y * w4.y + g2.z * w4.z + g2.w * w4.w;
        acc3 += g3.x * w4.x + g3.y * w4.y + g3.z * w4.z + g3.w * w4.w;
    }

    const int obase = bid * IPB;
    out[(obase + rq     ) * HID + h] = acc0;
    out[(obase + rq +  4) * HID + h] = acc1;
    out[(obase + rq +  8) * HID + h] = acc2;
    out[(obase + rq + 12) * HID + h] = acc3;
}

extern "C" void kernel_launch(void* const* d_in, const int* in_sizes, int n_in,
                              void* d_out, int out_size, void* d_ws, size_t ws_size,
                              hipStream_t stream) {
    // inputs: 0=hidden_state (unused), 1=obs1 (unused), 2=obs2, 3=W, 4=b
    const float* obs2 = (const float*)d_in[2];
    const float* W    = (const float*)d_in[3];
    const float* b    = (const float*)d_in[4];
    float* out        = (float*)d_out;
    (void)in_sizes; (void)n_in; (void)out_size; (void)d_ws; (void)ws_size;

    hipLaunchKernelGGL(pool_kernel, dim3(NB), dim3(BLOCK), 0, stream,
                       obs2, W, b, out);
}